// Round 6
// baseline (299.167 us; speedup 1.0000x reference)
//
#include <hip/hip_runtime.h>
#include <hip/hip_bf16.h>
#include <cstdint>

// Problem constants
#define TOK   64
#define INF   4096
#define OUTF  11008
#define KCHUNKS 128      // INF / 32
#define QCNT  16         // split-K factor -> K_block = 256
#define NCHB  172        // OUTF / 64 channels per block
#define KC    8          // k32-chunks per block

using bf16x8  = __attribute__((ext_vector_type(8))) __bf16;
using floatx4 = __attribute__((ext_vector_type(4))) float;

union B8u { uint32_t u[4]; uint4 q; bf16x8 v; };

// pack two fp32 into one dword of two truncated bf16 (elem a = low half)
__device__ __forceinline__ uint32_t hi2(float a, float b) {
    return (__float_as_uint(a) >> 16) | (__float_as_uint(b) & 0xffff0000u);
}
// residual after bf16 truncation (exact in fp32)
__device__ __forceinline__ float losub(float x) {
    return x - __uint_as_float(__float_as_uint(x) & 0xffff0000u);
}
__device__ __forceinline__ void packW(float4 a, float4 b, B8u& wh, B8u& wl) {
    wh.u[0] = hi2(a.x, a.y);  wh.u[1] = hi2(a.z, a.w);
    wh.u[2] = hi2(b.x, b.y);  wh.u[3] = hi2(b.z, b.w);
    wl.u[0] = hi2(losub(a.x), losub(a.y));
    wl.u[1] = hi2(losub(a.z), losub(a.w));
    wl.u[2] = hi2(losub(b.x), losub(b.y));
    wl.u[3] = hi2(losub(b.z), losub(b.w));
}

// fine-grained vmem wait that does NOT drain the whole queue
template<int N> __device__ __forceinline__ void vmwait() {
    asm volatile("s_waitcnt vmcnt(%0)" :: "n"(N) : "memory");
}

// ---------------------------------------------------------------------------
// k_prep_x: fp32 x[64][4096] -> bf16 hi/lo arrays in MFMA A-fragment order.
// uint4 index = (mt*128 + kc)*64 + lane ; elem j: x[mt*16+(lane&15)][kc*32+(lane>>4)*8+j]
// ---------------------------------------------------------------------------
__global__ __launch_bounds__(256) void k_prep_x(const float* __restrict__ x,
        unsigned short* __restrict__ xh, unsigned short* __restrict__ xl) {
    int idx  = blockIdx.x * 256 + threadIdx.x;          // 0..262143
    int j    = idx & 7;
    int lane = (idx >> 3) & 63;
    int kc   = (idx >> 9) & 127;
    int mt   = idx >> 16;
    int row  = mt * 16 + (lane & 15);
    int col  = kc * 32 + ((lane >> 4) << 3) + j;
    float v  = x[(size_t)row * INF + col];
    uint32_t u = __float_as_uint(v);
    float lo = losub(v);
    xh[idx] = (unsigned short)(u >> 16);
    xl[idx] = (unsigned short)(__float_as_uint(lo) >> 16);
}

// ---------------------------------------------------------------------------
// k_lora_t: tm[t][r] = sum_k x[t][k] * A[r][k].  grid (64 tokens, 4 rgroups).
// ---------------------------------------------------------------------------
__global__ __launch_bounds__(256) void k_lora_t(const float* __restrict__ x,
        const float* __restrict__ A, float* __restrict__ tm) {
    int t = blockIdx.x, wv = threadIdx.x >> 6, lane = threadIdx.x & 63;
    int r = blockIdx.y * 4 + wv;
    const float4* xr = (const float4*)(x + (size_t)t * INF);
    const float4* ar = (const float4*)(A + (size_t)r * INF);
    float s = 0.f;
#pragma unroll
    for (int i = 0; i < INF / 4 / 64; ++i) {
        float4 a = xr[lane + i * 64], b = ar[lane + i * 64];
        s += a.x * b.x + a.y * b.y + a.z * b.z + a.w * b.w;
    }
#pragma unroll
    for (int off = 32; off > 0; off >>= 1) s += __shfl_down(s, off);
    if (lane == 0) tm[t * 16 + r] = s;
}

// ---------------------------------------------------------------------------
// k_main: y = x @ W^T via 16x16x32 bf16 MFMA, fp32 emulated hi/lo:
//   x*w ~= xh*wh + xh*wl + xl*wh
// BARRIER-FREE W PIPELINE: each wave DMAs (global_load_lds, dense 16-line
// sources) the 16 W rows that only it reads -> wave-private LDS ring, no
// __syncthreads on the W path. The K-loop keeps 3 slots (6 KB/wave, 24 KB/CU)
// permanently in flight with s_waitcnt vmcnt(6) -- the queue never drains.
// x slab (shared by all waves) staged once with the kernel's single barrier.
// XOR granule swizzle makes DMA sources dense AND ds_read_b128 conflict-free.
// ---------------------------------------------------------------------------
template<bool ATOMIC>
__global__ __launch_bounds__(256, 1) void k_main(const float* __restrict__ W,
        const uint4* __restrict__ xh, const uint4* __restrict__ xl,
        const float* __restrict__ scale, float* __restrict__ part,
        float* __restrict__ out) {
    __shared__ uint4 xsl[2][4][KC][64];   // 64 KB: [hl][mt][kc][lane]
    __shared__ uint4 wring[4][4][128];    // 32 KB: [wave][slot][row*8 + pos]

    const int tid  = threadIdx.x;
    const int lane = tid & 63;
    const int wv   = tid >> 6;
    const int quad = lane >> 4;
    const int rr   = lane & 15;           // row within wave's 16 channels
    const int nb   = blockIdx.x % NCHB;
    const int q    = blockIdx.x / NCHB;   // 0..QCNT-1

    // W DMA lane mapping: 1 KB/issue = 8 rows x 128 B (2 full lines/row).
    // position pos=lane&7 within row stores global granule pos^(row&7).
    const int subrow = (lane >> 3) & 7;
    const int gglob  = (lane & 7) ^ subrow;
    const float* Wq  = W + (size_t)(nb * 64 + wv * 16) * INF + q * (KC * 32);

    // ---- x slab DMA: 16 issues/wave (shared -> needs the one barrier) ----
#pragma unroll
    for (int t = 0; t < 16; ++t) {
        int j  = wv * 16 + t;
        int hl = j >> 5, mt = (j >> 3) & 3, kc = j & 7;
        const uint4* src = (hl ? xl : xh)
            + ((size_t)(mt * KCHUNKS + q * KC + kc) * 64 + lane);
        __builtin_amdgcn_global_load_lds(
            (const __attribute__((address_space(1))) uint32_t*)src,
            (__attribute__((address_space(3))) uint32_t*)&xsl[hl][mt][kc][0],
            16, 0, 0);
    }
    // ---- W prologue: slots 0..2 (wave-private; barrier drains them early) --
#pragma unroll
    for (int s = 0; s < 3; ++s) {
#pragma unroll
        for (int i = 0; i < 2; ++i) {
            const float* src = Wq + (size_t)(i * 8 + subrow) * INF + s * 32 + gglob * 4;
            __builtin_amdgcn_global_load_lds(
                (const __attribute__((address_space(1))) uint32_t*)src,
                (__attribute__((address_space(3))) uint32_t*)&wring[wv][s][i * 64],
                16, 0, 0);
        }
    }
    __syncthreads();   // the ONLY barrier: x slab resident

    floatx4 acc[4] = {};

#pragma unroll
    for (int kc = 0; kc < KC; ++kc) {
        // issue slot kc+3 into phys (kc+3)&3 (read at kc-1, program-order safe)
        if (kc + 3 < KC) {
            int s = (kc + 3) & 3;
#pragma unroll
            for (int i = 0; i < 2; ++i) {
                const float* src = Wq + (size_t)(i * 8 + subrow) * INF
                                 + (kc + 3) * 32 + gglob * 4;
                __builtin_amdgcn_global_load_lds(
                    (const __attribute__((address_space(1))) uint32_t*)src,
                    (__attribute__((address_space(3))) uint32_t*)&wring[wv][s][i * 64],
                    16, 0, 0);
            }
        }
        // wait ONLY for slot kc; keep up to 3 newer slots in flight
        {
            int lft = KC - 1 - kc;
            int wc  = (lft > 3 ? 3 : lft) * 2;
            if (wc == 6) vmwait<6>();
            else if (wc == 4) vmwait<4>();
            else if (wc == 2) vmwait<2>();
            else vmwait<0>();
        }
        const uint4* slot = &wring[wv][kc & 3][0];
        uint4 wf0 = slot[rr * 8 + ((quad * 2)     ^ (rr & 7))];
        uint4 wf1 = slot[rr * 8 + ((quad * 2 + 1) ^ (rr & 7))];
        B8u wh, wl;
        packW(*(const float4*)&wf0, *(const float4*)&wf1, wh, wl);
#pragma unroll
        for (int mt = 0; mt < 4; ++mt) {
            B8u ah, al;
            ah.q = xsl[0][mt][kc][lane];
            al.q = xsl[1][mt][kc][lane];
            acc[mt] = __builtin_amdgcn_mfma_f32_16x16x32_bf16(ah.v, wh.v, acc[mt], 0, 0, 0);
            acc[mt] = __builtin_amdgcn_mfma_f32_16x16x32_bf16(ah.v, wl.v, acc[mt], 0, 0, 0);
            acc[mt] = __builtin_amdgcn_mfma_f32_16x16x32_bf16(al.v, wh.v, acc[mt], 0, 0, 0);
        }
    }

    // C/D layout (16x16, m89): col = lane&15 (= channel), row = quad*4 + reg (= token)
    int ch = nb * 64 + wv * 16 + rr;
#pragma unroll
    for (int mt = 0; mt < 4; ++mt) {
        int token = mt * 16 + quad * 4;
#pragma unroll
        for (int r = 0; r < 4; ++r) {
            if constexpr (ATOMIC) {
                atomicAdd(&out[(size_t)(token + r) * OUTF + ch], scale[ch] * acc[mt][r]);
            } else {
                part[((size_t)q * TOK + token + r) * OUTF + ch] = acc[mt][r];
            }
        }
    }
}

// ---------------------------------------------------------------------------
// k_post: out[t][o] = scale[o]*sum_q part[q][t][o] + sum_r tm[t][r]*B[o][r] + bias[o]
// ---------------------------------------------------------------------------
__global__ __launch_bounds__(256) void k_post(const float* __restrict__ part,
        const float* __restrict__ scale, const float* __restrict__ bias,
        const float* __restrict__ lB, const float* __restrict__ tm,
        float* __restrict__ out) {
    int o = blockIdx.x * 256 + threadIdx.x;
    int t = blockIdx.y;
    if (o >= OUTF) return;
    float s = 0.f;
#pragma unroll
    for (int qq = 0; qq < QCNT; ++qq)
        s += part[((size_t)qq * TOK + t) * OUTF + o];
    const float4* Br = (const float4*)(lB + (size_t)o * 16);
    const float4* tr = (const float4*)(tm + (size_t)t * 16);
    float l = 0.f;
#pragma unroll
    for (int i = 0; i < 4; ++i) {
        float4 b = Br[i], tt = tr[i];
        l += b.x * tt.x + b.y * tt.y + b.z * tt.z + b.w * tt.w;
    }
    out[(size_t)t * OUTF + o] = s * scale[o] + l + bias[o];
}

// Fallback pre-init for the atomic path: out = lora + bias, main adds scale*y.
__global__ __launch_bounds__(256) void k_pre(const float* __restrict__ bias,
        const float* __restrict__ lB, const float* __restrict__ tm,
        float* __restrict__ out) {
    int o = blockIdx.x * 256 + threadIdx.x;
    int t = blockIdx.y;
    if (o >= OUTF) return;
    const float4* Br = (const float4*)(lB + (size_t)o * 16);
    const float4* tr = (const float4*)(tm + (size_t)t * 16);
    float l = 0.f;
#pragma unroll
    for (int i = 0; i < 4; ++i) {
        float4 b = Br[i], tt = tr[i];
        l += b.x * tt.x + b.y * tt.y + b.z * tt.z + b.w * tt.w;
    }
    out[(size_t)t * OUTF + o] = l + bias[o];
}

extern "C" void kernel_launch(void* const* d_in, const int* in_sizes, int n_in,
                              void* d_out, int out_size, void* d_ws, size_t ws_size,
                              hipStream_t stream) {
    const float* x     = (const float*)d_in[0];
    const float* W     = (const float*)d_in[1];
    const float* scale = (const float*)d_in[2];
    const float* lA    = (const float*)d_in[3];
    const float* lB    = (const float*)d_in[4];
    const float* bias  = (const float*)d_in[5];
    float* out = (float*)d_out;

    char* ws = (char*)d_ws;
    unsigned short* xh = (unsigned short*)(ws);            // 512 KB
    unsigned short* xl = (unsigned short*)(ws + 524288);   // 512 KB
    float* tm   = (float*)(ws + 1048576);                  // 4 KB
    float* part = (float*)(ws + 1052672);                  // 45.1 MB
    const size_t need = 1052672 + (size_t)QCNT * TOK * OUTF * 4;

    k_prep_x<<<1024, 256, 0, stream>>>(x, xh, xl);
    k_lora_t<<<dim3(TOK, 4), 256, 0, stream>>>(x, lA, tm);

    if (ws_size >= need) {
        k_main<false><<<NCHB * QCNT, 256, 0, stream>>>(W, (const uint4*)xh,
                (const uint4*)xl, scale, part, out);
        k_post<<<dim3(43, TOK), 256, 0, stream>>>(part, scale, bias, lB, tm, out);
    } else {
        k_pre<<<dim3(43, TOK), 256, 0, stream>>>(bias, lB, tm, out);
        k_main<true><<<NCHB * QCNT, 256, 0, stream>>>(W, (const uint4*)xh,
                (const uint4*)xl, scale, nullptr, out);
    }
}